// Round 8
// baseline (291.257 us; speedup 1.0000x reference)
//
#include <hip/hip_runtime.h>
#include <math.h>

typedef __attribute__((ext_vector_type(8))) short short8;
typedef __attribute__((ext_vector_type(16))) float f32x16;

#define D      128
#define NSEG   128
#define SEGC   800           // candidates per segment (multiple of 32)
#define NT     25            // SEGC / 32
#define TILE_C 32
#define KTOP   10
#define CAP    128
#define DELTA  3.0f
#define NPAD   (NSEG * SEGC + TILE_C)   // +32 rows for last-tile prefetch overrun (== 102432)
#define ROWU   144           // ushorts per padded row (288 B): 128 data + x2w hi/lo + zeros
#define TUNITS (TILE_C * 18) // 576 16B-units per tile

// ---------- helpers ----------
__device__ __forceinline__ ushort f2bf(float f) {
    uint u = __float_as_uint(f);
    uint r = (u + 0x7FFFu + ((u >> 16) & 1u)) >> 16;
    return (ushort)r;
}

__device__ __forceinline__ uint packx2(float x2w) {
    ushort h = f2bf(x2w);
    float hf = __uint_as_float(((uint)h) << 16);
    ushort lo = f2bf(x2w - hf);
    return (uint)h | ((uint)lo << 16);
}

__device__ __forceinline__ void insert10(float s, float v, float ls[KTOP], float lw[KTOP]) {
    ls[9] = s; lw[9] = v;
#pragma unroll
    for (int p = 9; p > 0; --p) {
        bool sw = ls[p] < ls[p - 1];
        float ts = sw ? ls[p - 1] : ls[p];
        float tl = sw ? ls[p]     : ls[p - 1];
        float tv = sw ? lw[p - 1] : lw[p];
        float tu = sw ? lw[p]     : lw[p - 1];
        ls[p] = ts; ls[p - 1] = tl;
        lw[p] = tv; lw[p - 1] = tu;
    }
}

__device__ __forceinline__ void insert10s(float s, float ms[KTOP]) {
    ms[9] = s;
#pragma unroll
    for (int p = 9; p > 0; --p) {
        float a = fminf(ms[p - 1], ms[p]);
        float b = fmaxf(ms[p - 1], ms[p]);
        ms[p - 1] = a; ms[p] = b;
    }
}

// ---------- fused prep: candidates (padded 288B rows, bf16 + x2w hi/lo), queries, cnt zero ----------
__global__ void prep_kernel(const float* __restrict__ Xt, const float* __restrict__ X,
                            const float* __restrict__ w,
                            ushort* __restrict__ Xbp, ushort* __restrict__ Xtb,
                            float* __restrict__ x2wf, float* __restrict__ q2f,
                            int* __restrict__ cnt, int n, int m, int nblocksA) {
    int wave = threadIdx.x >> 6, lane = threadIdx.x & 63;
    if ((int)blockIdx.x < nblocksA) {
        int row = blockIdx.x * 4 + wave;
        if (row >= NPAD) return;
        ushort* rowp = Xbp + (size_t)row * ROWU;
        if (row < n) {
            float2 v = ((const float2*)X)[(size_t)row * 64 + lane];
            ((ushort2*)rowp)[lane] = make_ushort2(f2bf(v.x), f2bf(v.y));
            float s = v.x * v.x + v.y * v.y;
#pragma unroll
            for (int o = 32; o; o >>= 1) s += __shfl_xor(s, o, 64);
            float x2w = s - w[row];
            if (lane == 0) x2wf[row] = x2w;
            if (lane < 8) ((uint*)rowp)[64 + lane] = (lane == 0) ? packx2(x2w) : 0u;
        } else {
            ((ushort2*)rowp)[lane] = make_ushort2(0, 0);      // sentinel: zero data
            if (lane < 8) ((uint*)rowp)[64 + lane] = (lane == 0) ? packx2(1e30f) : 0u;
        }
    } else {
        int qb = blockIdx.x - nblocksA;
        int row = qb * 4 + wave;
        int tid = qb * 256 + threadIdx.x;
        if (tid < m) cnt[tid] = 0;
        if (row >= m) return;
        float2 v = ((const float2*)Xt)[(size_t)row * 64 + lane];
        ((ushort2*)Xtb)[(size_t)row * 64 + lane] = make_ushort2(f2bf(v.x), f2bf(v.y));
        float s = v.x * v.x + v.y * v.y;
#pragma unroll
        for (int o = 32; o; o >>= 1) s += __shfl_xor(s, o, 64);
        if (lane == 0) q2f[row] = s;
    }
}

__device__ __forceinline__ void emit_cand(int q, int c, int* cnt, int* buf) {
    int pos = atomicAdd(&cnt[q], 1);
    if (pos < CAP) buf[q * CAP + pos] = c;
}

// ---------- main GEMM pass ----------
// 512 blocks = 128 segs x 4 query-blocks = 2 blocks/CU. Block: 4 waves x 128 queries each.
// Wave tile: 32 cands x 128 queries per k-step (4 MFMAs), B in regs.
// A: NO LDS, NO __syncthreads. Each lane streams its own 16B A-fragment global->VGPR,
// register-double-buffered one full tile ahead (acur/anxt[9]); the in-flight loads have a
// full tile (~2300 cyc) before consumption, so vmcnt waits are fully covered. The block's
// 4 waves read the same 18KB tile => L1 reuse; a raw s_barrier (no memory semantics
// needed) keeps them phased. acc = q.x - 0.5*x2w  =>  s = -2*acc.
template<int PASS>
__global__ __launch_bounds__(256, 2) void nd_pass(
        const ushort* __restrict__ Xbp, const ushort* __restrict__ Xtb,
        const float* __restrict__ tau, float* __restrict__ minbuf,
        int* __restrict__ cnt, int* __restrict__ buf, int m) {
    const int t = threadIdx.x;
    const int l = t & 63, wv = t >> 6;
    const int half = l >> 5;
    const int seg = blockIdx.x;
    const int qbase = blockIdx.y * 512 + wv * 128;
    const int q0 = qbase + (l & 31);                 // query for qsub 0 (qsub s -> +32*s)
    const int tile0 = seg * NT;

    // preload B fragments: [kstep][qsub]
    short8 Bf[9][4];
#pragma unroll
    for (int s = 0; s < 8; ++s)
#pragma unroll
        for (int qs = 0; qs < 4; ++qs)
            Bf[s][qs] = *(const short8*)(Xtb + (size_t)(q0 + qs * 32) * D + s * 16 + half * 8);
    {
        short8 z = (short8)(short)0;
        if (l < 32) { z[0] = (short)0xBF00; z[1] = (short)0xBF00; }  // -0.5 at k=128,129
#pragma unroll
        for (int qs = 0; qs < 4; ++qs) Bf[8][qs] = z;
    }

    float tp[4];
    float mx[4];
#pragma unroll
    for (int qs = 0; qs < 4; ++qs) {
        tp[qs] = (PASS == 2) ? (-0.5f * tau[q0 + qs * 32]) : 0.f;
        mx[qs] = -INFINITY;
    }

    // per-lane A stream: row = l&31 (18 units/row), unit kb = ks*2+half (ks<8) or 16+half
    const short8* Xg = (const short8*)Xbp;
    const int rowu = (l & 31) * 18 + half;

    short8 acur[9], anxt[9];
    {
        const size_t gb = (size_t)tile0 * TUNITS + rowu;
#pragma unroll
        for (int ks = 0; ks < 9; ++ks)
            acur[ks] = Xg[gb + ((ks < 8) ? ks * 2 : 16)];
    }

    for (int t2 = 0; t2 < NT; ++t2) {
        const size_t gn = (size_t)(tile0 + t2 + 1) * TUNITS + rowu;  // pad tile covers overrun
        f32x16 acc0 = (f32x16)0.f, acc1 = (f32x16)0.f, acc2 = (f32x16)0.f, acc3 = (f32x16)0.f;
#pragma unroll
        for (int ks = 0; ks < 9; ++ks) {
            anxt[ks] = Xg[gn + ((ks < 8) ? ks * 2 : 16)];
            short8 a = acur[ks];
            acc0 = __builtin_amdgcn_mfma_f32_32x32x16_bf16(a, Bf[ks][0], acc0, 0, 0, 0);
            acc1 = __builtin_amdgcn_mfma_f32_32x32x16_bf16(a, Bf[ks][1], acc1, 0, 0, 0);
            acc2 = __builtin_amdgcn_mfma_f32_32x32x16_bf16(a, Bf[ks][2], acc2, 0, 0, 0);
            acc3 = __builtin_amdgcn_mfma_f32_32x32x16_bf16(a, Bf[ks][3], acc3, 0, 0, 0);
        }
#pragma unroll
        for (int ks = 0; ks < 9; ++ks) acur[ks] = anxt[ks];

        // epilogue: per-qsub max of acc (s = -2*acc, so max acc == min s)
        float h[4];
#pragma unroll
        for (int qs = 0; qs < 4; ++qs) h[qs] = -INFINITY;
#pragma unroll
        for (int r = 0; r < 16; ++r) {
            h[0] = fmaxf(h[0], acc0[r]); h[1] = fmaxf(h[1], acc1[r]);
            h[2] = fmaxf(h[2], acc2[r]); h[3] = fmaxf(h[3], acc3[r]);
        }
        if (PASS == 1) {
#pragma unroll
            for (int qs = 0; qs < 4; ++qs) mx[qs] = fmaxf(mx[qs], h[qs]);
        } else {
            const int base = (tile0 + t2) * TILE_C;
            if (__any(h[0] >= tp[0])) {
#pragma unroll
                for (int r = 0; r < 16; ++r)
                    if (acc0[r] >= tp[0]) emit_cand(q0,      base + (r & 3) + 8 * (r >> 2) + 4 * half, cnt, buf);
            }
            if (__any(h[1] >= tp[1])) {
#pragma unroll
                for (int r = 0; r < 16; ++r)
                    if (acc1[r] >= tp[1]) emit_cand(q0 + 32, base + (r & 3) + 8 * (r >> 2) + 4 * half, cnt, buf);
            }
            if (__any(h[2] >= tp[2])) {
#pragma unroll
                for (int r = 0; r < 16; ++r)
                    if (acc2[r] >= tp[2]) emit_cand(q0 + 64, base + (r & 3) + 8 * (r >> 2) + 4 * half, cnt, buf);
            }
            if (__any(h[3] >= tp[3])) {
#pragma unroll
                for (int r = 0; r < 16; ++r)
                    if (acc3[r] >= tp[3]) emit_cand(q0 + 96, base + (r & 3) + 8 * (r >> 2) + 4 * half, cnt, buf);
            }
        }
        __builtin_amdgcn_s_barrier();   // raw rendezvous: keep the 4 waves L1-phased
    }

    if (PASS == 1) {
        size_t rowi = (size_t)(seg * 2 + half) * m;
#pragma unroll
        for (int qs = 0; qs < 4; ++qs)
            minbuf[rowi + q0 + qs * 32] = -2.f * mx[qs];
    }
}

// ---------- tau: 10th smallest of 2*NSEG stream-mins per query, + margin ----------
// block = 256 thr = 64 queries x 4 parts; each part scans 64 stream entries (coalesced),
// partial top-10s merged via LDS, one thread per query takes 10th of 40.
__global__ void tau_kernel(const float* __restrict__ minbuf, float* __restrict__ tau, int m) {
    __shared__ float sh[64 * 40];
    const int qi = threadIdx.x & 63, part = threadIdx.x >> 6;
    const int q = blockIdx.x * 64 + qi;
    float ms[KTOP];
#pragma unroll
    for (int e = 0; e < KTOP; ++e) ms[e] = INFINITY;
#pragma unroll 4
    for (int i = 0; i < 64; ++i) {
        float v = minbuf[(size_t)(part * 64 + i) * m + q];
        if (v < ms[9]) insert10s(v, ms);
    }
#pragma unroll
    for (int e = 0; e < KTOP; ++e) sh[qi * 40 + part * 10 + e] = ms[e];
    __syncthreads();
    if (threadIdx.x < 64) {
        const int qq = blockIdx.x * 64 + threadIdx.x;
        float fs[KTOP];
#pragma unroll
        for (int e = 0; e < KTOP; ++e) fs[e] = INFINITY;
        for (int x = 0; x < 40; ++x) {
            float v = sh[threadIdx.x * 40 + x];
            if (v < fs[9]) insert10s(v, fs);
        }
        tau[qq] = fs[9] + DELTA;
    }
}

// ---------- exact fp32 rescore ----------
__global__ void rescore_kernel(const float* __restrict__ Xtf, const float* __restrict__ Xf,
                               const float* __restrict__ w, const float* __restrict__ x2wf,
                               const float* __restrict__ q2f, const int* __restrict__ cnt,
                               const int* __restrict__ buf, float* __restrict__ out, int m) {
    __shared__ float sS[CAP], sW[CAP];
    const int q = blockIdx.x, l = threadIdx.x;
    const int c = min(cnt[q], CAP);
    const bool v0 = l < c, v1 = l + 64 < c;
    const int j0 = v0 ? buf[q * CAP + l] : 0;
    const int j1 = v1 ? buf[q * CAP + l + 64] : 0;
    const float4* Q4 = (const float4*)Xtf + (size_t)q * 32;
    const float4* A4 = (const float4*)Xf + (size_t)j0 * 32;
    const float4* B4 = (const float4*)Xf + (size_t)j1 * 32;
    float acc0 = 0.f, acc1 = 0.f;
#pragma unroll 8
    for (int d = 0; d < 32; ++d) {
        float4 qv = Q4[d];
        float4 a = A4[d], b = B4[d];
        acc0 = fmaf(qv.x, a.x, fmaf(qv.y, a.y, fmaf(qv.z, a.z, fmaf(qv.w, a.w, acc0))));
        acc1 = fmaf(qv.x, b.x, fmaf(qv.y, b.y, fmaf(qv.z, b.z, fmaf(qv.w, b.w, acc1))));
    }
    sS[l]      = v0 ? (x2wf[j0] - 2.f * acc0) : INFINITY;
    sW[l]      = v0 ? w[j0] : 0.f;
    sS[l + 64] = v1 ? (x2wf[j1] - 2.f * acc1) : INFINITY;
    sW[l + 64] = v1 ? w[j1] : 0.f;
    __syncthreads();
    if (l == 0) {
        float ls[KTOP], lw[KTOP];
#pragma unroll
        for (int e = 0; e < KTOP; ++e) { ls[e] = INFINITY; lw[e] = 0.f; }
        for (int i = 0; i < c; ++i)
            if (sS[i] < ls[9]) insert10(sS[i], sW[i], ls, lw);
        float q2v = q2f[q];
        float mxv = -INFINITY;
#pragma unroll
        for (int e = 0; e < KTOP; ++e) {
            if (ls[e] < 1e30f) {
                float d2 = fmaxf(q2v + ls[e] + lw[e], 0.f);
                mxv = fmaxf(mxv, lw[e] - sqrtf(d2));
            }
        }
        out[q] = mxv;
    }
}

// ---------- launch ----------
extern "C" void kernel_launch(void* const* d_in, const int* in_sizes, int n_in,
                              void* d_out, int out_size, void* d_ws, size_t ws_size,
                              hipStream_t stream) {
    const float* Xt = (const float*)d_in[0];
    const float* X  = (const float*)d_in[1];
    const float* w  = (const float*)d_in[2];
    const int m = in_sizes[0] / D;   // 2048
    const int n = in_sizes[1] / D;   // 100000

    auto align256 = [](size_t x) { return (x + 255) & ~(size_t)255; };
    char* p = (char*)d_ws;
    ushort* Xbp  = (ushort*)p;  p += align256((size_t)NPAD * ROWU * 2);     // ~29.5 MB
    ushort* Xtb  = (ushort*)p;  p += align256((size_t)m * D * 2);
    float*  x2wf = (float*)p;   p += align256((size_t)n * 4);
    float*  q2f  = (float*)p;   p += align256((size_t)m * 4);
    float*  minb = (float*)p;   p += align256((size_t)2 * NSEG * m * 4);    // 2 MB
    float*  tau  = (float*)p;   p += align256((size_t)m * 4);
    int*    cnt  = (int*)p;     p += align256((size_t)m * 4);
    int*    buf  = (int*)p;     p += align256((size_t)m * CAP * 4);

    const int nblocksA = (NPAD + 3) / 4;
    const int nblocksB = (m + 3) / 4;
    prep_kernel<<<nblocksA + nblocksB, 256, 0, stream>>>(Xt, X, w, Xbp, Xtb, x2wf, q2f, cnt, n, m, nblocksA);

    dim3 grid(NSEG, m / 512);
    nd_pass<1><<<grid, 256, 0, stream>>>(Xbp, Xtb, tau, minb, cnt, buf, m);
    tau_kernel<<<m / 64, 256, 0, stream>>>(minb, tau, m);
    nd_pass<2><<<grid, 256, 0, stream>>>(Xbp, Xtb, tau, minb, cnt, buf, m);
    rescore_kernel<<<m, 64, 0, stream>>>(Xt, X, w, x2wf, q2f, cnt, buf, (float*)d_out, m);
}

// Round 9
// 286.545 us; speedup vs baseline: 1.0164x; 1.0164x over previous
//
#include <hip/hip_runtime.h>
#include <math.h>

typedef __attribute__((ext_vector_type(8))) short short8;
typedef __attribute__((ext_vector_type(16))) float f32x16;

#define D      128
#define NSEG   128
#define SEGC   800           // candidates per segment (multiple of 32)
#define NT     25            // SEGC / 32
#define NPAIR  12            // 25 tiles = 12 pairs + 1 tail
#define TILE_C 32
#define KTOP   10
#define CAP    128
#define DELTA  3.0f
#define NPAD   (NSEG * SEGC + TILE_C)   // +32 rows for last-tile prefetch overrun (== 102432)
#define ROWU   144           // ushorts per padded row (288 B): 128 data + x2w hi/lo + zeros
#define TUNITS (TILE_C * 18) // 576 16B-units per tile
#define BUFU   (TUNITS * 8)  // 4608 ushorts per LDS buffer

// LDS swizzle: unit (r,kb) stored at r*18 + (kb ^ ((r>>2)&1)).
__device__ __forceinline__ int lds_unit(int u) {
    int r = u / 18, kb = u % 18;
    return r * 18 + (kb ^ ((r >> 2) & 1));
}

// ---------- helpers ----------
__device__ __forceinline__ ushort f2bf(float f) {
    uint u = __float_as_uint(f);
    uint r = (u + 0x7FFFu + ((u >> 16) & 1u)) >> 16;
    return (ushort)r;
}

__device__ __forceinline__ uint packx2(float x2w) {
    ushort h = f2bf(x2w);
    float hf = __uint_as_float(((uint)h) << 16);
    ushort lo = f2bf(x2w - hf);
    return (uint)h | ((uint)lo << 16);
}

__device__ __forceinline__ void insert10(float s, float v, float ls[KTOP], float lw[KTOP]) {
    ls[9] = s; lw[9] = v;
#pragma unroll
    for (int p = 9; p > 0; --p) {
        bool sw = ls[p] < ls[p - 1];
        float ts = sw ? ls[p - 1] : ls[p];
        float tl = sw ? ls[p]     : ls[p - 1];
        float tv = sw ? lw[p - 1] : lw[p];
        float tu = sw ? lw[p]     : lw[p - 1];
        ls[p] = ts; ls[p - 1] = tl;
        lw[p] = tv; lw[p - 1] = tu;
    }
}

__device__ __forceinline__ void insert10s(float s, float ms[KTOP]) {
    ms[9] = s;
#pragma unroll
    for (int p = 9; p > 0; --p) {
        float a = fminf(ms[p - 1], ms[p]);
        float b = fmaxf(ms[p - 1], ms[p]);
        ms[p - 1] = a; ms[p] = b;
    }
}

// ---------- fused prep ----------
__global__ void prep_kernel(const float* __restrict__ Xt, const float* __restrict__ X,
                            const float* __restrict__ w,
                            ushort* __restrict__ Xbp, ushort* __restrict__ Xtb,
                            float* __restrict__ x2wf, float* __restrict__ q2f,
                            int* __restrict__ cnt, int n, int m, int nblocksA) {
    int wave = threadIdx.x >> 6, lane = threadIdx.x & 63;
    if ((int)blockIdx.x < nblocksA) {
        int row = blockIdx.x * 4 + wave;
        if (row >= NPAD) return;
        ushort* rowp = Xbp + (size_t)row * ROWU;
        if (row < n) {
            float2 v = ((const float2*)X)[(size_t)row * 64 + lane];
            ((ushort2*)rowp)[lane] = make_ushort2(f2bf(v.x), f2bf(v.y));
            float s = v.x * v.x + v.y * v.y;
#pragma unroll
            for (int o = 32; o; o >>= 1) s += __shfl_xor(s, o, 64);
            float x2w = s - w[row];
            if (lane == 0) x2wf[row] = x2w;
            if (lane < 8) ((uint*)rowp)[64 + lane] = (lane == 0) ? packx2(x2w) : 0u;
        } else {
            ((ushort2*)rowp)[lane] = make_ushort2(0, 0);      // sentinel: zero data
            if (lane < 8) ((uint*)rowp)[64 + lane] = (lane == 0) ? packx2(1e30f) : 0u;
        }
    } else {
        int qb = blockIdx.x - nblocksA;
        int row = qb * 4 + wave;
        int tid = qb * 256 + threadIdx.x;
        if (tid < m) cnt[tid] = 0;
        if (row >= m) return;
        float2 v = ((const float2*)Xt)[(size_t)row * 64 + lane];
        ((ushort2*)Xtb)[(size_t)row * 64 + lane] = make_ushort2(f2bf(v.x), f2bf(v.y));
        float s = v.x * v.x + v.y * v.y;
#pragma unroll
        for (int o = 32; o; o >>= 1) s += __shfl_xor(s, o, 64);
        if (lane == 0) q2f[row] = s;
    }
}

__device__ __forceinline__ void emit_cand(int q, int c, int* cnt, int* buf) {
    int pos = atomicAdd(&cnt[q], 1);
    if (pos < CAP) buf[q * CAP + pos] = c;
}

// ---------- main GEMM pass ----------
// 512 blocks = 128 segs x 4 query-blocks = 2 blocks/CU. Block: 4 waves x 128 queries each.
// Wave tile: 32 cands x 128 queries per k-step (4 MFMAs), B in regs.
// A staging: coalesced global->VGPR + ds_write_b128, FOUR LDS buffers, ONE __syncthreads
// per TWO tiles (write bufs p&1*{2,3}; barrier; load next pair; compute both).
// Buffer-reuse hazard separated by the intervening pair's barrier. acc = q.x - 0.5*x2w.
template<int PASS>
__global__ __launch_bounds__(256, 2) void nd_pass(
        const ushort* __restrict__ Xbp, const ushort* __restrict__ Xtb,
        const float* __restrict__ tau, float* __restrict__ minbuf,
        int* __restrict__ cnt, int* __restrict__ buf, int m) {
    __shared__ __align__(16) ushort As[4 * BUFU];   // 4 x 9216 B = 36.9 KB

    const int t = threadIdx.x;
    const int l = t & 63, wv = t >> 6;
    const int half = l >> 5;
    const int seg = blockIdx.x;
    const int qbase = blockIdx.y * 512 + wv * 128;
    const int q0 = qbase + (l & 31);                 // query for qsub 0 (qsub s -> +32*s)
    const int tile0 = seg * NT;
    const int halfx = half ^ ((l >> 2) & 1);         // swizzled k-unit selector for reads

    // preload B fragments: [kstep][qsub]
    short8 Bf[9][4];
#pragma unroll
    for (int s = 0; s < 8; ++s)
#pragma unroll
        for (int qs = 0; qs < 4; ++qs)
            Bf[s][qs] = *(const short8*)(Xtb + (size_t)(q0 + qs * 32) * D + s * 16 + half * 8);
    {
        short8 z = (short8)(short)0;
        if (l < 32) { z[0] = (short)0xBF00; z[1] = (short)0xBF00; }  // -0.5 at k=128,129
#pragma unroll
        for (int qs = 0; qs < 4; ++qs) Bf[8][qs] = z;
    }

    float tp[4];
    float mx[4];
#pragma unroll
    for (int qs = 0; qs < 4; ++qs) {
        tp[qs] = (PASS == 2) ? (-0.5f * tau[q0 + qs * 32]) : 0.f;
        mx[qs] = -INFINITY;
    }

    // staging mapping: thread t owns global units t, 256+t, and (t<64) 512+t
    const int u0 = t, u1 = 256 + t, u2 = 512 + (t & 63);
    const int L0 = lds_unit(u0) * 8, L1 = lds_unit(u1) * 8, L2 = lds_unit(u2) * 8;
    const uint4* Xg = (const uint4*)Xbp;

    // compute one staged tile + fused epilogue
    auto compute_tile = [&](const ushort* Lb, int tileIdx) {
        f32x16 acc0 = (f32x16)0.f, acc1 = (f32x16)0.f, acc2 = (f32x16)0.f, acc3 = (f32x16)0.f;
#pragma unroll
        for (int ks = 0; ks < 9; ++ks) {
            const int kb = (ks < 8) ? (ks * 2 + halfx) : (16 + halfx);
            short8 a = *(const short8*)&Lb[((l & 31) * 18 + kb) * 8];
            acc0 = __builtin_amdgcn_mfma_f32_32x32x16_bf16(a, Bf[ks][0], acc0, 0, 0, 0);
            acc1 = __builtin_amdgcn_mfma_f32_32x32x16_bf16(a, Bf[ks][1], acc1, 0, 0, 0);
            acc2 = __builtin_amdgcn_mfma_f32_32x32x16_bf16(a, Bf[ks][2], acc2, 0, 0, 0);
            acc3 = __builtin_amdgcn_mfma_f32_32x32x16_bf16(a, Bf[ks][3], acc3, 0, 0, 0);
        }
        float h[4];
#pragma unroll
        for (int qs = 0; qs < 4; ++qs) h[qs] = -INFINITY;
#pragma unroll
        for (int r = 0; r < 16; ++r) {
            h[0] = fmaxf(h[0], acc0[r]); h[1] = fmaxf(h[1], acc1[r]);
            h[2] = fmaxf(h[2], acc2[r]); h[3] = fmaxf(h[3], acc3[r]);
        }
        if (PASS == 1) {
#pragma unroll
            for (int qs = 0; qs < 4; ++qs) mx[qs] = fmaxf(mx[qs], h[qs]);
        } else {
            const int base = tileIdx * TILE_C;
            if (__any(h[0] >= tp[0])) {
#pragma unroll
                for (int r = 0; r < 16; ++r)
                    if (acc0[r] >= tp[0]) emit_cand(q0,      base + (r & 3) + 8 * (r >> 2) + 4 * half, cnt, buf);
            }
            if (__any(h[1] >= tp[1])) {
#pragma unroll
                for (int r = 0; r < 16; ++r)
                    if (acc1[r] >= tp[1]) emit_cand(q0 + 32, base + (r & 3) + 8 * (r >> 2) + 4 * half, cnt, buf);
            }
            if (__any(h[2] >= tp[2])) {
#pragma unroll
                for (int r = 0; r < 16; ++r)
                    if (acc2[r] >= tp[2]) emit_cand(q0 + 64, base + (r & 3) + 8 * (r >> 2) + 4 * half, cnt, buf);
            }
            if (__any(h[3] >= tp[3])) {
#pragma unroll
                for (int r = 0; r < 16; ++r)
                    if (acc3[r] >= tp[3]) emit_cand(q0 + 96, base + (r & 3) + 8 * (r >> 2) + 4 * half, cnt, buf);
            }
        }
    };

    // load tiles 0,1 into regs
    uint4 ra0, ra1, ra2 = make_uint4(0, 0, 0, 0);
    uint4 rb0, rb1, rb2 = make_uint4(0, 0, 0, 0);
    {
        const size_t ga = (size_t)tile0 * TUNITS;
        const size_t gb = (size_t)(tile0 + 1) * TUNITS;
        ra0 = Xg[ga + u0]; ra1 = Xg[ga + u1]; if (t < 64) ra2 = Xg[ga + u2];
        rb0 = Xg[gb + u0]; rb1 = Xg[gb + u1]; if (t < 64) rb2 = Xg[gb + u2];
    }

    int t2 = 0;
    for (int p = 0; p < NPAIR; ++p) {
        ushort* LA = &As[((p & 1) * 2 + 0) * BUFU];
        ushort* LB = &As[((p & 1) * 2 + 1) * BUFU];
        *(uint4*)&LA[L0] = ra0; *(uint4*)&LA[L1] = ra1; if (t < 64) *(uint4*)&LA[L2] = ra2;
        *(uint4*)&LB[L0] = rb0; *(uint4*)&LB[L1] = rb1; if (t < 64) *(uint4*)&LB[L2] = rb2;
        __syncthreads();

        const size_t ga = (size_t)(tile0 + t2 + 2) * TUNITS;   // pad rows cover final overrun
        ra0 = Xg[ga + u0]; ra1 = Xg[ga + u1]; if (t < 64) ra2 = Xg[ga + u2];
        if (p + 1 < NPAIR) {
            const size_t gb = (size_t)(tile0 + t2 + 3) * TUNITS;
            rb0 = Xg[gb + u0]; rb1 = Xg[gb + u1]; if (t < 64) rb2 = Xg[gb + u2];
        }

        compute_tile(LA, tile0 + t2);
        compute_tile(LB, tile0 + t2 + 1);
        t2 += 2;
    }
    {   // tail tile (t2 == 24): ra holds it; buffer 0's last readers were pair p=10,
        // separated by pair p=11's barrier.
        ushort* LA = &As[0];
        *(uint4*)&LA[L0] = ra0; *(uint4*)&LA[L1] = ra1; if (t < 64) *(uint4*)&LA[L2] = ra2;
        __syncthreads();
        compute_tile(LA, tile0 + t2);
    }

    if (PASS == 1) {
        size_t rowi = (size_t)(seg * 2 + half) * m;
#pragma unroll
        for (int qs = 0; qs < 4; ++qs)
            minbuf[rowi + q0 + qs * 32] = -2.f * mx[qs];
    }
}

// ---------- tau: 10th smallest of 2*NSEG stream-mins per query, + margin ----------
__global__ void tau_kernel(const float* __restrict__ minbuf, float* __restrict__ tau, int m) {
    __shared__ float sh[64 * 40];
    const int qi = threadIdx.x & 63, part = threadIdx.x >> 6;
    const int q = blockIdx.x * 64 + qi;
    float ms[KTOP];
#pragma unroll
    for (int e = 0; e < KTOP; ++e) ms[e] = INFINITY;
#pragma unroll 4
    for (int i = 0; i < 64; ++i) {
        float v = minbuf[(size_t)(part * 64 + i) * m + q];
        if (v < ms[9]) insert10s(v, ms);
    }
#pragma unroll
    for (int e = 0; e < KTOP; ++e) sh[qi * 40 + part * 10 + e] = ms[e];
    __syncthreads();
    if (threadIdx.x < 64) {
        const int qq = blockIdx.x * 64 + threadIdx.x;
        float fs[KTOP];
#pragma unroll
        for (int e = 0; e < KTOP; ++e) fs[e] = INFINITY;
        for (int x = 0; x < 40; ++x) {
            float v = sh[threadIdx.x * 40 + x];
            if (v < fs[9]) insert10s(v, fs);
        }
        tau[qq] = fs[9] + DELTA;
    }
}

// ---------- exact fp32 rescore ----------
__global__ void rescore_kernel(const float* __restrict__ Xtf, const float* __restrict__ Xf,
                               const float* __restrict__ w, const float* __restrict__ x2wf,
                               const float* __restrict__ q2f, const int* __restrict__ cnt,
                               const int* __restrict__ buf, float* __restrict__ out, int m) {
    __shared__ float sS[CAP], sW[CAP];
    const int q = blockIdx.x, l = threadIdx.x;
    const int c = min(cnt[q], CAP);
    const bool v0 = l < c, v1 = l + 64 < c;
    const int j0 = v0 ? buf[q * CAP + l] : 0;
    const int j1 = v1 ? buf[q * CAP + l + 64] : 0;
    const float4* Q4 = (const float4*)Xtf + (size_t)q * 32;
    const float4* A4 = (const float4*)Xf + (size_t)j0 * 32;
    const float4* B4 = (const float4*)Xf + (size_t)j1 * 32;
    float acc0 = 0.f, acc1 = 0.f;
#pragma unroll 8
    for (int d = 0; d < 32; ++d) {
        float4 qv = Q4[d];
        float4 a = A4[d], b = B4[d];
        acc0 = fmaf(qv.x, a.x, fmaf(qv.y, a.y, fmaf(qv.z, a.z, fmaf(qv.w, a.w, acc0))));
        acc1 = fmaf(qv.x, b.x, fmaf(qv.y, b.y, fmaf(qv.z, b.z, fmaf(qv.w, b.w, acc1))));
    }
    sS[l]      = v0 ? (x2wf[j0] - 2.f * acc0) : INFINITY;
    sW[l]      = v0 ? w[j0] : 0.f;
    sS[l + 64] = v1 ? (x2wf[j1] - 2.f * acc1) : INFINITY;
    sW[l + 64] = v1 ? w[j1] : 0.f;
    __syncthreads();
    if (l == 0) {
        float ls[KTOP], lw[KTOP];
#pragma unroll
        for (int e = 0; e < KTOP; ++e) { ls[e] = INFINITY; lw[e] = 0.f; }
        for (int i = 0; i < c; ++i)
            if (sS[i] < ls[9]) insert10(sS[i], sW[i], ls, lw);
        float q2v = q2f[q];
        float mxv = -INFINITY;
#pragma unroll
        for (int e = 0; e < KTOP; ++e) {
            if (ls[e] < 1e30f) {
                float d2 = fmaxf(q2v + ls[e] + lw[e], 0.f);
                mxv = fmaxf(mxv, lw[e] - sqrtf(d2));
            }
        }
        out[q] = mxv;
    }
}

// ---------- launch ----------
extern "C" void kernel_launch(void* const* d_in, const int* in_sizes, int n_in,
                              void* d_out, int out_size, void* d_ws, size_t ws_size,
                              hipStream_t stream) {
    const float* Xt = (const float*)d_in[0];
    const float* X  = (const float*)d_in[1];
    const float* w  = (const float*)d_in[2];
    const int m = in_sizes[0] / D;   // 2048
    const int n = in_sizes[1] / D;   // 100000

    auto align256 = [](size_t x) { return (x + 255) & ~(size_t)255; };
    char* p = (char*)d_ws;
    ushort* Xbp  = (ushort*)p;  p += align256((size_t)NPAD * ROWU * 2);     // ~29.5 MB
    ushort* Xtb  = (ushort*)p;  p += align256((size_t)m * D * 2);
    float*  x2wf = (float*)p;   p += align256((size_t)n * 4);
    float*  q2f  = (float*)p;   p += align256((size_t)m * 4);
    float*  minb = (float*)p;   p += align256((size_t)2 * NSEG * m * 4);    // 2 MB
    float*  tau  = (float*)p;   p += align256((size_t)m * 4);
    int*    cnt  = (int*)p;     p += align256((size_t)m * 4);
    int*    buf  = (int*)p;     p += align256((size_t)m * CAP * 4);

    const int nblocksA = (NPAD + 3) / 4;
    const int nblocksB = (m + 3) / 4;
    prep_kernel<<<nblocksA + nblocksB, 256, 0, stream>>>(Xt, X, w, Xbp, Xtb, x2wf, q2f, cnt, n, m, nblocksA);

    dim3 grid(NSEG, m / 512);
    nd_pass<1><<<grid, 256, 0, stream>>>(Xbp, Xtb, tau, minb, cnt, buf, m);
    tau_kernel<<<m / 64, 256, 0, stream>>>(minb, tau, m);
    nd_pass<2><<<grid, 256, 0, stream>>>(Xbp, Xtb, tau, minb, cnt, buf, m);
    rescore_kernel<<<m, 64, 0, stream>>>(Xt, X, w, x2wf, q2f, cnt, buf, (float*)d_out, m);
}